// Round 10
// baseline (1554.680 us; speedup 1.0000x reference)
//
#include <hip/hip_runtime.h>

#define HW 3136      // 56*56
#define SHS 232      // LDS row stride in kernel B (v7-proven conflict-free)

// ---------------- Kernel A: grouped 3x3 conv + bias + BN-a + ReLU ----------------
// Block = (b, i, kc[4 k's], 14-row strip). Wave = one k (wave-uniform weights ->
// s_loads), lane = pixel (coalesced full-row loads, zero line redundancy).
// x-halo via 2 shfl per row; y/x zero-pad natural (invalid lanes load 0).
// No LDS, no barriers; ~40 VGPR -> 8 blocks/CU.
__global__ __launch_bounds__(256, 8) void gconv3(
    const float* __restrict__ in,    // [32,256,56,56]
    const float* __restrict__ gw,    // [4,64,4,3,3] (i,k,cc,dy,dx)
    const float* __restrict__ gb,    // [256] flat i*64+k
    const float* __restrict__ bng, const float* __restrict__ bnb,
    const float* __restrict__ bnm, const float* __restrict__ bnv,
    float* __restrict__ h)           // [32,256,56,56]
{
    // grid 8192 = 8 xcd * 1024. The 4 conv-indices i (which read the SAME input
    // channels for a given kc) land on one XCD -> L2-shared input rows.
    const int idx   = blockIdx.x;
    const int xcd   = idx & 7;
    const int i     = xcd & 3;
    const int kcl   = xcd >> 2;
    const int rest  = idx >> 3;      // 0..1023
    const int b     = rest >> 5;     // 0..31
    const int r2    = rest & 31;
    const int strip = r2 >> 3;       // 0..3 -> rows [strip*14, +14)
    const int kch   = r2 & 7;
    const int kc    = kch * 2 + kcl; // 0..15

    const int l  = threadIdx.x & 63;                 // lane = pixel
    const int wv = threadIdx.x >> 6;                 // wave = k within chunk
    const int k  = __builtin_amdgcn_readfirstlane(kc * 4 + wv);  // wave-uniform
    const int ys = strip * 14;

    const int cmid = i * 64 + k;
    const float* wk = gw + (size_t)cmid * 36;        // uniform -> scalar loads

    float acc[14];
#pragma unroll
    for (int r = 0; r < 14; ++r) acc[r] = 0.f;

    const float* chp0 = in + ((size_t)(b * 256 + k * 4)) * HW;

#pragma unroll
    for (int cc = 0; cc < 4; ++cc) {
        const float w00 = wk[cc*9+0], w01 = wk[cc*9+1], w02 = wk[cc*9+2];
        const float w10 = wk[cc*9+3], w11 = wk[cc*9+4], w12 = wk[cc*9+5];
        const float w20 = wk[cc*9+6], w21 = wk[cc*9+7], w22 = wk[cc*9+8];
        const float* chp = chp0 + cc * HW;
#pragma unroll
        for (int ry = 0; ry < 16; ++ry) {
            const int gy = ys - 1 + ry;              // input row
            float v = 0.f;
            if ((unsigned)gy < 56u && l < 56) v = chp[gy * 56 + l];  // coalesced
            const float Ls = __shfl_up(v, 1);        // px l-1 (garbage lane 0)
            const float R  = __shfl_down(v, 1);      // px l+1 (lane 55 <- lane56's 0)
            const float L  = (l == 0) ? 0.f : Ls;    // x zero-pad
#pragma unroll
            for (int dy = 0; dy < 3; ++dy) {
                const int orr = ry - dy;             // local out row
                if (orr < 0 || orr > 13) continue;   // dead-code after unroll
                const float wa = (dy == 0) ? w00 : (dy == 1) ? w10 : w20;
                const float wb = (dy == 0) ? w01 : (dy == 1) ? w11 : w21;
                const float wc = (dy == 0) ? w02 : (dy == 1) ? w12 : w22;
                acc[orr] = fmaf(wc, R, fmaf(wb, v, fmaf(wa, L, acc[orr])));
            }
        }
    }

    // bias + BN-a + ReLU -> h (coalesced 56-lane row stores)
    const float sc = bng[cmid] * rsqrtf(bnv[cmid] + 1e-5f);
    const float sh = fmaf(gb[cmid], sc, bnb[cmid] - bnm[cmid] * sc);
    if (l < 56) {
        float* op = h + ((size_t)(b * 256 + cmid)) * HW + ys * 56 + l;
#pragma unroll
        for (int r = 0; r < 14; ++r)
            op[r * 56] = fmaxf(fmaf(acc[r], sc, sh), 0.f);
    }
}

// ---------------- Kernel B: grouped 1x1 conv + bias + BN-b + ReLU ----------------
// Stage the block's 64ch x 224px h-slice into LDS (flat coalesced float4), then
// v7's proven conflict-free broadcast GEMM. Safe IN-PLACE (h==out): the full slice
// is staged before the barrier; writes touch only this block's slice.
__global__ __launch_bounds__(256, 2) void pconv(
    const float* __restrict__ h,     // [32,256,56,56]
    const float* __restrict__ pw,    // [256,64]
    const float* __restrict__ pb,    // [256]
    const float* __restrict__ bng, const float* __restrict__ bnb,
    const float* __restrict__ bnm, const float* __restrict__ bnv,
    float* __restrict__ out)         // [32,256,56,56] (may alias h)
{
    __shared__ float sHt[64 * SHS];  // 59392 B -> 2 blocks/CU

    const int blk  = blockIdx.x;     // 1792 = 32*4*14
    const int b    = blk / 56;
    const int rem  = blk - b * 56;
    const int g    = rem / 14;
    const int tile = rem - g * 14;
    const int pxb  = tile * 224;
    const int tid  = threadIdx.x;

    // stage: 64 ch x 56 float4, flat index it*256+tid (incremental c/px4 decode)
    {
        int c   = tid / 56;
        int px4 = tid - c * 56;
        const float* base = h + ((size_t)(b * 256 + g * 64)) * HW + pxb;
#pragma unroll
        for (int it = 0; it < 14; ++it) {
            const float4 v = *(const float4*)(base + (size_t)c * HW + px4 * 4);
            *(float4*)&sHt[c * SHS + px4 * 4] = v;
            c += 4; px4 += 32;
            if (px4 >= 56) { px4 -= 56; c += 1; }
        }
    }
    __syncthreads();

    // v7 phase-2: 64x224 GEMM, 4 outs x 14 px per thread, conflict-free b64 reads
    const int og = tid >> 4;         // 0..15 -> out channels og*4..+3
    const int pg = tid & 15;         // 0..15 -> px p0..p0+13
    const int p0 = pg * 14;

    float a2[4][14];
#pragma unroll
    for (int i = 0; i < 4; ++i)
#pragma unroll
        for (int xx = 0; xx < 14; ++xx) a2[i][xx] = 0.f;

    const float* wp = pw + (size_t)(g * 64 + og * 4) * 64;

    for (int c4 = 0; c4 < 64; c4 += 4) {
        const float4 wv0 = *(const float4*)(wp + 0 * 64 + c4);  // L1-resident
        const float4 wv1 = *(const float4*)(wp + 1 * 64 + c4);
        const float4 wv2 = *(const float4*)(wp + 2 * 64 + c4);
        const float4 wv3 = *(const float4*)(wp + 3 * 64 + c4);
        const float w0a[4] = {wv0.x, wv0.y, wv0.z, wv0.w};
        const float w1a[4] = {wv1.x, wv1.y, wv1.z, wv1.w};
        const float w2a[4] = {wv2.x, wv2.y, wv2.z, wv2.w};
        const float w3a[4] = {wv3.x, wv3.y, wv3.z, wv3.w};
#pragma unroll
        for (int q2 = 0; q2 < 4; ++q2) {
            const float* hrow = &sHt[(c4 + q2) * SHS + p0];
            float hr[14];
#pragma unroll
            for (int j = 0; j < 7; ++j) {
                float2 v = *(const float2*)&hrow[2 * j];  // 16 addrs, conflict-free
                hr[2*j] = v.x; hr[2*j+1] = v.y;
            }
            const float wa = w0a[q2], wb = w1a[q2], wc = w2a[q2], wd = w3a[q2];
#pragma unroll
            for (int xx = 0; xx < 14; ++xx) {
                a2[0][xx] = fmaf(wa, hr[xx], a2[0][xx]);
                a2[1][xx] = fmaf(wb, hr[xx], a2[1][xx]);
                a2[2][xx] = fmaf(wc, hr[xx], a2[2][xx]);
                a2[3][xx] = fmaf(wd, hr[xx], a2[3][xx]);
            }
        }
    }

    // bias + BN-b + ReLU -> out
#pragma unroll
    for (int i = 0; i < 4; ++i) {
        const int o = g * 64 + og * 4 + i;
        const float sc = bng[o] * rsqrtf(bnv[o] + 1e-5f);
        const float sh = fmaf(pb[o], sc, bnb[o] - bnm[o] * sc);
        float* op = out + ((size_t)(b * 256 + o)) * HW + pxb + p0;
#pragma unroll
        for (int j = 0; j < 7; ++j) {
            float v0 = fmaxf(fmaf(a2[i][2*j],   sc, sh), 0.f);
            float v1 = fmaxf(fmaf(a2[i][2*j+1], sc, sh), 0.f);
            *(float2*)(op + 2*j) = make_float2(v0, v1);
        }
    }
}

extern "C" void kernel_launch(void* const* d_in, const int* in_sizes, int n_in,
                              void* d_out, int out_size, void* d_ws, size_t ws_size,
                              hipStream_t stream) {
    const float* x     = (const float*)d_in[0];
    const float* w1    = (const float*)d_in[1];
    const float* b1    = (const float*)d_in[2];
    const float* bn1ag = (const float*)d_in[3];
    const float* bn1ab = (const float*)d_in[4];
    const float* bn1am = (const float*)d_in[5];
    const float* bn1av = (const float*)d_in[6];
    const float* pw1   = (const float*)d_in[7];
    const float* pb1   = (const float*)d_in[8];
    const float* bn1bg = (const float*)d_in[9];
    const float* bn1bb = (const float*)d_in[10];
    const float* bn1bm = (const float*)d_in[11];
    const float* bn1bv = (const float*)d_in[12];
    const float* w2    = (const float*)d_in[13];
    const float* b2    = (const float*)d_in[14];
    const float* bn2ag = (const float*)d_in[15];
    const float* bn2ab = (const float*)d_in[16];
    const float* bn2am = (const float*)d_in[17];
    const float* bn2av = (const float*)d_in[18];
    const float* pw2   = (const float*)d_in[19];
    const float* pb2   = (const float*)d_in[20];
    const float* bn2bg = (const float*)d_in[21];
    const float* bn2bb = (const float*)d_in[22];
    const float* bn2bm = (const float*)d_in[23];
    const float* bn2bv = (const float*)d_in[24];

    float* mid  = (float*)d_ws;      // 32*256*56*56*4 = 102,760,448 B
    float* outp = (float*)d_out;     // doubles as h-scratch before the final write

    const int gridA = 8192;          // (xcd:i,kcl) x (b,strip,kch)
    const int gridB = 1792;          // (b,g,tile)

    // stage 1: x -> h1(d_out) -> mid(ws)
    gconv3<<<gridA, 256, 0, stream>>>(x, w1, b1, bn1ag, bn1ab, bn1am, bn1av, outp);
    pconv <<<gridB, 256, 0, stream>>>(outp, pw1, pb1, bn1bg, bn1bb, bn1bm, bn1bv, mid);
    // stage 2: mid -> h2(d_out) -> out(d_out, in-place)
    gconv3<<<gridA, 256, 0, stream>>>(mid, w2, b2, bn2ag, bn2ab, bn2am, bn2av, outp);
    pconv <<<gridB, 256, 0, stream>>>(outp, pw2, pb2, bn2bg, bn2bb, bn2bm, bn2bv, outp);
}

// Round 11
// 1194.139 us; speedup vs baseline: 1.3019x; 1.3019x over previous
//
#include <hip/hip_runtime.h>

#define HW 3136      // 56*56
#define SHS 232      // LDS row stride in kernel B (v7-proven conflict-free)

// ---------------- Kernel A: grouped 3x3 conv + bias + BN-a + ReLU ----------------
// Block = (b, i, kc[4 k's], 14-row strip). Wave = one k (wave-uniform weights ->
// s_loads), lane = pixel (coalesced full-row loads, zero line redundancy).
// x-halo via 2 shfl per row; y/x zero-pad natural (invalid lanes load 0).
// No LDS, no barriers. v10 fix: launch_bounds(256,4) -> 128-VGPR cap; the (256,8)
// 64-VGPR cap made the allocator spill acc[14] (WRITE 1.28 GB, 623us).
__global__ __launch_bounds__(256, 4) void gconv3(
    const float* __restrict__ in,    // [32,256,56,56]
    const float* __restrict__ gw,    // [4,64,4,3,3] (i,k,cc,dy,dx)
    const float* __restrict__ gb,    // [256] flat i*64+k
    const float* __restrict__ bng, const float* __restrict__ bnb,
    const float* __restrict__ bnm, const float* __restrict__ bnv,
    float* __restrict__ h)           // [32,256,56,56]
{
    // grid 8192 = 8 xcd * 1024. The 4 conv-indices i (which read the SAME input
    // channels for a given kc) land on one XCD -> L2-shared input rows.
    const int idx   = blockIdx.x;
    const int xcd   = idx & 7;
    const int i     = xcd & 3;
    const int kcl   = xcd >> 2;
    const int rest  = idx >> 3;      // 0..1023
    const int b     = rest >> 5;     // 0..31
    const int r2    = rest & 31;
    const int strip = r2 >> 3;       // 0..3 -> rows [strip*14, +14)
    const int kch   = r2 & 7;
    const int kc    = kch * 2 + kcl; // 0..15

    const int l  = threadIdx.x & 63;                 // lane = pixel
    const int wv = threadIdx.x >> 6;                 // wave = k within chunk
    const int k  = __builtin_amdgcn_readfirstlane(kc * 4 + wv);  // wave-uniform
    const int ys = strip * 14;

    const int cmid = i * 64 + k;
    const float* wk = gw + (size_t)cmid * 36;        // uniform -> scalar loads

    float acc[14];
#pragma unroll
    for (int r = 0; r < 14; ++r) acc[r] = 0.f;

    const float* chp0 = in + ((size_t)(b * 256 + k * 4)) * HW;

#pragma unroll
    for (int cc = 0; cc < 4; ++cc) {
        const float w00 = wk[cc*9+0], w01 = wk[cc*9+1], w02 = wk[cc*9+2];
        const float w10 = wk[cc*9+3], w11 = wk[cc*9+4], w12 = wk[cc*9+5];
        const float w20 = wk[cc*9+6], w21 = wk[cc*9+7], w22 = wk[cc*9+8];
        const float* chp = chp0 + cc * HW;
#pragma unroll
        for (int ry = 0; ry < 16; ++ry) {
            const int gy = ys - 1 + ry;              // input row
            float v = 0.f;
            if ((unsigned)gy < 56u && l < 56) v = chp[gy * 56 + l];  // coalesced
            const float Ls = __shfl_up(v, 1);        // px l-1 (garbage lane 0)
            const float R  = __shfl_down(v, 1);      // px l+1 (lane 55 <- lane56's 0)
            const float L  = (l == 0) ? 0.f : Ls;    // x zero-pad
#pragma unroll
            for (int dy = 0; dy < 3; ++dy) {
                const int orr = ry - dy;             // local out row
                if (orr < 0 || orr > 13) continue;   // dead-code after unroll
                const float wa = (dy == 0) ? w00 : (dy == 1) ? w10 : w20;
                const float wb = (dy == 0) ? w01 : (dy == 1) ? w11 : w21;
                const float wc = (dy == 0) ? w02 : (dy == 1) ? w12 : w22;
                acc[orr] = fmaf(wc, R, fmaf(wb, v, fmaf(wa, L, acc[orr])));
            }
        }
    }

    // bias + BN-a + ReLU -> h (coalesced 56-lane row stores)
    const float sc = bng[cmid] * rsqrtf(bnv[cmid] + 1e-5f);
    const float sh = fmaf(gb[cmid], sc, bnb[cmid] - bnm[cmid] * sc);
    if (l < 56) {
        float* op = h + ((size_t)(b * 256 + cmid)) * HW + ys * 56 + l;
#pragma unroll
        for (int r = 0; r < 14; ++r)
            op[r * 56] = fmaxf(fmaf(acc[r], sc, sh), 0.f);
    }
}

// ---------------- Kernel B: grouped 1x1 conv + bias + BN-b + ReLU ----------------
// Stage the block's 64ch x 224px h-slice into LDS (flat coalesced float4), then
// v7's proven conflict-free broadcast GEMM. Safe IN-PLACE (h==out): the full slice
// is staged before the barrier; writes touch only this block's slice.
__global__ __launch_bounds__(256, 2) void pconv(
    const float* __restrict__ h,     // [32,256,56,56]
    const float* __restrict__ pw,    // [256,64]
    const float* __restrict__ pb,    // [256]
    const float* __restrict__ bng, const float* __restrict__ bnb,
    const float* __restrict__ bnm, const float* __restrict__ bnv,
    float* __restrict__ out)         // [32,256,56,56] (may alias h)
{
    __shared__ float sHt[64 * SHS];  // 59392 B -> 2 blocks/CU

    const int blk  = blockIdx.x;     // 1792 = 32*4*14
    const int b    = blk / 56;
    const int rem  = blk - b * 56;
    const int g    = rem / 14;
    const int tile = rem - g * 14;
    const int pxb  = tile * 224;
    const int tid  = threadIdx.x;

    // stage: 64 ch x 56 float4, flat index it*256+tid (incremental c/px4 decode)
    {
        int c   = tid / 56;
        int px4 = tid - c * 56;
        const float* base = h + ((size_t)(b * 256 + g * 64)) * HW + pxb;
#pragma unroll
        for (int it = 0; it < 14; ++it) {
            const float4 v = *(const float4*)(base + (size_t)c * HW + px4 * 4);
            *(float4*)&sHt[c * SHS + px4 * 4] = v;
            c += 4; px4 += 32;
            if (px4 >= 56) { px4 -= 56; c += 1; }
        }
    }
    __syncthreads();

    // v7 phase-2: 64x224 GEMM, 4 outs x 14 px per thread, conflict-free b64 reads
    const int og = tid >> 4;         // 0..15 -> out channels og*4..+3
    const int pg = tid & 15;         // 0..15 -> px p0..p0+13
    const int p0 = pg * 14;

    float a2[4][14];
#pragma unroll
    for (int i = 0; i < 4; ++i)
#pragma unroll
        for (int xx = 0; xx < 14; ++xx) a2[i][xx] = 0.f;

    const float* wp = pw + (size_t)(g * 64 + og * 4) * 64;

    for (int c4 = 0; c4 < 64; c4 += 4) {
        const float4 wv0 = *(const float4*)(wp + 0 * 64 + c4);  // L1-resident
        const float4 wv1 = *(const float4*)(wp + 1 * 64 + c4);
        const float4 wv2 = *(const float4*)(wp + 2 * 64 + c4);
        const float4 wv3 = *(const float4*)(wp + 3 * 64 + c4);
        const float w0a[4] = {wv0.x, wv0.y, wv0.z, wv0.w};
        const float w1a[4] = {wv1.x, wv1.y, wv1.z, wv1.w};
        const float w2a[4] = {wv2.x, wv2.y, wv2.z, wv2.w};
        const float w3a[4] = {wv3.x, wv3.y, wv3.z, wv3.w};
#pragma unroll
        for (int q2 = 0; q2 < 4; ++q2) {
            const float* hrow = &sHt[(c4 + q2) * SHS + p0];
            float hr[14];
#pragma unroll
            for (int j = 0; j < 7; ++j) {
                float2 v = *(const float2*)&hrow[2 * j];  // 16 addrs, conflict-free
                hr[2*j] = v.x; hr[2*j+1] = v.y;
            }
            const float wa = w0a[q2], wb = w1a[q2], wc = w2a[q2], wd = w3a[q2];
#pragma unroll
            for (int xx = 0; xx < 14; ++xx) {
                a2[0][xx] = fmaf(wa, hr[xx], a2[0][xx]);
                a2[1][xx] = fmaf(wb, hr[xx], a2[1][xx]);
                a2[2][xx] = fmaf(wc, hr[xx], a2[2][xx]);
                a2[3][xx] = fmaf(wd, hr[xx], a2[3][xx]);
            }
        }
    }

    // bias + BN-b + ReLU -> out
#pragma unroll
    for (int i = 0; i < 4; ++i) {
        const int o = g * 64 + og * 4 + i;
        const float sc = bng[o] * rsqrtf(bnv[o] + 1e-5f);
        const float sh = fmaf(pb[o], sc, bnb[o] - bnm[o] * sc);
        float* op = out + ((size_t)(b * 256 + o)) * HW + pxb + p0;
#pragma unroll
        for (int j = 0; j < 7; ++j) {
            float v0 = fmaxf(fmaf(a2[i][2*j],   sc, sh), 0.f);
            float v1 = fmaxf(fmaf(a2[i][2*j+1], sc, sh), 0.f);
            *(float2*)(op + 2*j) = make_float2(v0, v1);
        }
    }
}

extern "C" void kernel_launch(void* const* d_in, const int* in_sizes, int n_in,
                              void* d_out, int out_size, void* d_ws, size_t ws_size,
                              hipStream_t stream) {
    const float* x     = (const float*)d_in[0];
    const float* w1    = (const float*)d_in[1];
    const float* b1    = (const float*)d_in[2];
    const float* bn1ag = (const float*)d_in[3];
    const float* bn1ab = (const float*)d_in[4];
    const float* bn1am = (const float*)d_in[5];
    const float* bn1av = (const float*)d_in[6];
    const float* pw1   = (const float*)d_in[7];
    const float* pb1   = (const float*)d_in[8];
    const float* bn1bg = (const float*)d_in[9];
    const float* bn1bb = (const float*)d_in[10];
    const float* bn1bm = (const float*)d_in[11];
    const float* bn1bv = (const float*)d_in[12];
    const float* w2    = (const float*)d_in[13];
    const float* b2    = (const float*)d_in[14];
    const float* bn2ag = (const float*)d_in[15];
    const float* bn2ab = (const float*)d_in[16];
    const float* bn2am = (const float*)d_in[17];
    const float* bn2av = (const float*)d_in[18];
    const float* pw2   = (const float*)d_in[19];
    const float* pb2   = (const float*)d_in[20];
    const float* bn2bg = (const float*)d_in[21];
    const float* bn2bb = (const float*)d_in[22];
    const float* bn2bm = (const float*)d_in[23];
    const float* bn2bv = (const float*)d_in[24];

    float* mid  = (float*)d_ws;      // 32*256*56*56*4 = 102,760,448 B
    float* outp = (float*)d_out;     // doubles as h-scratch before the final write

    const int gridA = 8192;          // (xcd:i,kcl) x (b,strip,kch)
    const int gridB = 1792;          // (b,g,tile)

    // stage 1: x -> h1(d_out) -> mid(ws)
    gconv3<<<gridA, 256, 0, stream>>>(x, w1, b1, bn1ag, bn1ab, bn1am, bn1av, outp);
    pconv <<<gridB, 256, 0, stream>>>(outp, pw1, pb1, bn1bg, bn1bb, bn1bm, bn1bv, mid);
    // stage 2: mid -> h2(d_out) -> out(d_out, in-place)
    gconv3<<<gridA, 256, 0, stream>>>(mid, w2, b2, bn2ag, bn2ab, bn2am, bn2av, outp);
    pconv <<<gridB, 256, 0, stream>>>(outp, pw2, pb2, bn2bg, bn2bb, bn2bm, bn2bv, outp);
}